// Round 6
// baseline (502.178 us; speedup 1.0000x reference)
//
#include <hip/hip_runtime.h>

typedef __attribute__((ext_vector_type(8))) short bf16x8;
typedef __attribute__((ext_vector_type(4))) float f32x4;

__device__ __forceinline__ unsigned short f2b(float f) {
    union { float f; unsigned int i; } u; u.f = f;
    return (unsigned short)((u.i + 0x7FFFu + ((u.i >> 16) & 1u)) >> 16);
}
__device__ __forceinline__ unsigned int packbf2(float a, float b) {
    return (unsigned int)f2b(a) | ((unsigned int)f2b(b) << 16);
}

// ---------------------------------------------------------------------------
// SpMM block (device fn): side[r,:] += vals[e] * ego_bf16[cols[e],:]
// (rows sorted). 256 edges per call (4 waves x 64). Metadata via v_readlane;
// row transition = scalar branch; depth-16 register prefetch queue.
// Order-independent across blocks (atomics).
// ---------------------------------------------------------------------------
__device__ __forceinline__ void spmm_block(
    const unsigned int* __restrict__ egob, const float* __restrict__ vals,
    const int* __restrict__ rows, const int* __restrict__ cols,
    float* __restrict__ side, int nnz, int blk)
{
    int tid = threadIdx.x;
    int wave = tid >> 6, lane = tid & 63;
    int e0 = blk * 256 + wave * 64;
    if (e0 >= nnz) return;

    int idx = e0 + lane;
    int last = nnz - 1;
    bool ok = idx < nnz;
    int safe = ok ? idx : last;
    int my_row = rows[safe];
    int my_col = cols[safe];
    float my_val = ok ? vals[safe] : 0.f;

    unsigned int pre[16];
    #pragma unroll
    for (int j = 0; j < 16; ++j) {
        unsigned int c = (unsigned int)__builtin_amdgcn_readlane(my_col, j);
        pre[j] = *(egob + ((size_t)c << 6) + lane);
    }

    float ax = 0.f, ay = 0.f;
    int cur = __builtin_amdgcn_readlane(my_row, 0);
    #pragma unroll
    for (int e = 0; e < 64; ++e) {
        int r = __builtin_amdgcn_readlane(my_row, e);
        float vv = __int_as_float(__builtin_amdgcn_readlane(__float_as_int(my_val), e));
        unsigned int u = pre[e & 15];
        if (e < 48) {
            unsigned int c = (unsigned int)__builtin_amdgcn_readlane(my_col, e + 16);
            pre[e & 15] = *(egob + ((size_t)c << 6) + lane);
        }
        if (r != cur) {
            atomicAdd(&side[(size_t)cur * 128 + lane * 2], ax);
            atomicAdd(&side[(size_t)cur * 128 + lane * 2 + 1], ay);
            ax = 0.f; ay = 0.f; cur = r;
        }
        ax = fmaf(vv, __uint_as_float(u << 16), ax);
        ay = fmaf(vv, __uint_as_float(u & 0xFFFF0000u), ay);
    }
    atomicAdd(&side[(size_t)cur * 128 + lane * 2], ax);
    atomicAdd(&side[(size_t)cur * 128 + lane * 2 + 1], ay);
}

#define LDAB 40   // bf16 row stride in LDS (80B rows -> 2-way conflicts only)

// ---------------------------------------------------------------------------
// gemm2 core: BM=64 x BN=128 tile, 256 threads = 4 waves as 2(m) x 2(n).
// C = act(A@W + bias [+R]) with optional fused row-LayerNorm (g,bta; N==128).
// ---------------------------------------------------------------------------
__device__ __forceinline__ void gemm2_core(
    const float* __restrict__ A, const float* __restrict__ W,
    const float* __restrict__ bias, const float* __restrict__ R,
    const float* __restrict__ g, const float* __restrict__ bta,
    float* __restrict__ C, int M, int N, int K, int act,
    int bm, int bn, unsigned short* As, unsigned short* Bs,
    float* redS, float* redSS)
{
    int tid = threadIdx.x, wave = tid >> 6, lane = tid & 63;
    int lm = lane & 15, quad = lane >> 4;
    int wm = wave >> 1, wn = wave & 1;

    f32x4 acc[2][4];
    #pragma unroll
    for (int i = 0; i < 2; ++i)
        #pragma unroll
        for (int j = 0; j < 4; ++j) acc[i][j] = (f32x4)(0.f);

    for (int k0 = 0; k0 < K; k0 += 32) {
        {
            int m = tid >> 2, kc = (tid & 3) * 8;
            const float* p = A + (size_t)(bm + m) * K + k0 + kc;
            float4 a0 = *(const float4*)p, a1 = *(const float4*)(p + 4);
            uint4 pk;
            pk.x = packbf2(a0.x, a0.y); pk.y = packbf2(a0.z, a0.w);
            pk.z = packbf2(a1.x, a1.y); pk.w = packbf2(a1.z, a1.w);
            *(uint4*)&As[m * LDAB + kc] = pk;
        }
        {
            int nn = tid & 127, kh = (tid >> 7) * 16;
            const float* p = W + (size_t)(k0 + kh) * N + bn + nn;
            float w[16];
            #pragma unroll
            for (int j = 0; j < 16; ++j) w[j] = p[(size_t)j * N];
            uint4 pk;
            pk.x = packbf2(w[0], w[1]);  pk.y = packbf2(w[2], w[3]);
            pk.z = packbf2(w[4], w[5]);  pk.w = packbf2(w[6], w[7]);
            *(uint4*)&Bs[nn * LDAB + kh] = pk;
            pk.x = packbf2(w[8], w[9]);  pk.y = packbf2(w[10], w[11]);
            pk.z = packbf2(w[12], w[13]); pk.w = packbf2(w[14], w[15]);
            *(uint4*)&Bs[nn * LDAB + kh + 8] = pk;
        }
        __syncthreads();
        bf16x8 af[2], bfr[4];
        #pragma unroll
        for (int mi = 0; mi < 2; ++mi)
            af[mi] = *(bf16x8*)&As[(wm * 32 + mi * 16 + lm) * LDAB + quad * 8];
        #pragma unroll
        for (int ni = 0; ni < 4; ++ni)
            bfr[ni] = *(bf16x8*)&Bs[(wn * 64 + ni * 16 + lm) * LDAB + quad * 8];
        #pragma unroll
        for (int mi = 0; mi < 2; ++mi)
            #pragma unroll
            for (int ni = 0; ni < 4; ++ni)
                acc[mi][ni] = __builtin_amdgcn_mfma_f32_16x16x32_bf16(
                    af[mi], bfr[ni], acc[mi][ni], 0, 0, 0);
        __syncthreads();
    }

    #pragma unroll
    for (int mi = 0; mi < 2; ++mi) {
        #pragma unroll
        for (int r = 0; r < 4; ++r) {
            int row = bm + wm * 32 + mi * 16 + quad * 4 + r;
            #pragma unroll
            for (int ni = 0; ni < 4; ++ni) {
                int col = bn + wn * 64 + ni * 16 + lm;
                float v = acc[mi][ni][r] + bias[col];
                if (R) v += R[(size_t)row * N + col];
                if (act) v = fmaxf(v, 0.f);
                acc[mi][ni][r] = v;
            }
        }
    }

    if (g) {
        #pragma unroll
        for (int mi = 0; mi < 2; ++mi) {
            #pragma unroll
            for (int r = 0; r < 4; ++r) {
                float s = 0.f, ss = 0.f;
                #pragma unroll
                for (int ni = 0; ni < 4; ++ni) {
                    float v = acc[mi][ni][r];
                    s += v; ss = fmaf(v, v, ss);
                }
                #pragma unroll
                for (int off = 1; off < 16; off <<= 1) {
                    s  += __shfl_xor(s, off, 64);
                    ss += __shfl_xor(ss, off, 64);
                }
                if (lm == 0) {
                    int lr = wm * 32 + mi * 16 + quad * 4 + r;
                    redS[wn * 64 + lr] = s;
                    redSS[wn * 64 + lr] = ss;
                }
            }
        }
        __syncthreads();
        #pragma unroll
        for (int mi = 0; mi < 2; ++mi) {
            #pragma unroll
            for (int r = 0; r < 4; ++r) {
                int lr = wm * 32 + mi * 16 + quad * 4 + r;
                int row = bm + lr;
                float s = redS[lr] + redS[64 + lr];
                float ss = redSS[lr] + redSS[64 + lr];
                float mean = s * (1.f / 128.f);
                float var = ss * (1.f / 128.f) - mean * mean;
                float rstd = rsqrtf(var + 1e-5f);
                #pragma unroll
                for (int ni = 0; ni < 4; ++ni) {
                    int col = wn * 64 + ni * 16 + lm;
                    float y = (acc[mi][ni][r] - mean) * rstd * g[col] + bta[col];
                    C[(size_t)row * 128 + col] = y;
                }
            }
        }
    } else {
        #pragma unroll
        for (int mi = 0; mi < 2; ++mi) {
            #pragma unroll
            for (int r = 0; r < 4; ++r) {
                int row = bm + wm * 32 + mi * 16 + quad * 4 + r;
                #pragma unroll
                for (int ni = 0; ni < 4; ++ni) {
                    int col = bn + wn * 64 + ni * 16 + lm;
                    C[(size_t)row * N + col] = acc[mi][ni][r];
                }
            }
        }
    }
}

// ---------------------------------------------------------------------------
// Bi-interaction core v2: BM=64 x BN=128 (full width -> each row panel staged
// ONCE). out = leaky((ego+side)@W1+b1) + leaky((ego*side)@W2+b2), K=N=128.
// 4 waves as 2(m) x 2(n). LDS: Us/Ms 64xLDAB + W1s/W2s 128xLDAB = 30720 B.
// ---------------------------------------------------------------------------
__device__ __forceinline__ void bi_core2(
    const float* __restrict__ ego, const float* __restrict__ side,
    const float* __restrict__ W1, const float* __restrict__ b1,
    const float* __restrict__ W2, const float* __restrict__ b2,
    float* __restrict__ out, int M, int bm,
    unsigned short* Us, unsigned short* Ms,
    unsigned short* W1s, unsigned short* W2s)
{
    int tid = threadIdx.x, wave = tid >> 6, lane = tid & 63;
    int lm = lane & 15, quad = lane >> 4;
    int wm = wave >> 1, wn = wave & 1;

    f32x4 acc1[2][4], acc2[2][4];
    #pragma unroll
    for (int i = 0; i < 2; ++i)
        #pragma unroll
        for (int j = 0; j < 4; ++j) { acc1[i][j] = (f32x4)(0.f); acc2[i][j] = (f32x4)(0.f); }

    for (int k0 = 0; k0 < 128; k0 += 32) {
        // stage A pair: 64 rows x 32 k; thread: m=tid>>2, kc=(tid&3)*8
        {
            int m = tid >> 2, kc = (tid & 3) * 8;
            int gm = bm + m;
            float e[8], s[8];
            if (gm < M) {
                const float* pe = ego + (size_t)gm * 128 + k0 + kc;
                const float* ps = side + (size_t)gm * 128 + k0 + kc;
                float4 e0 = *(const float4*)pe, e1 = *(const float4*)(pe + 4);
                float4 s0 = *(const float4*)ps, s1 = *(const float4*)(ps + 4);
                e[0]=e0.x; e[1]=e0.y; e[2]=e0.z; e[3]=e0.w;
                e[4]=e1.x; e[5]=e1.y; e[6]=e1.z; e[7]=e1.w;
                s[0]=s0.x; s[1]=s0.y; s[2]=s0.z; s[3]=s0.w;
                s[4]=s1.x; s[5]=s1.y; s[6]=s1.z; s[7]=s1.w;
            } else {
                #pragma unroll
                for (int j = 0; j < 8; ++j) { e[j] = 0.f; s[j] = 0.f; }
            }
            uint4 pu, pm;
            pu.x = packbf2(e[0]+s[0], e[1]+s[1]); pu.y = packbf2(e[2]+s[2], e[3]+s[3]);
            pu.z = packbf2(e[4]+s[4], e[5]+s[5]); pu.w = packbf2(e[6]+s[6], e[7]+s[7]);
            pm.x = packbf2(e[0]*s[0], e[1]*s[1]); pm.y = packbf2(e[2]*s[2], e[3]*s[3]);
            pm.z = packbf2(e[4]*s[4], e[5]*s[5]); pm.w = packbf2(e[6]*s[6], e[7]*s[7]);
            *(uint4*)&Us[m * LDAB + kc] = pu;
            *(uint4*)&Ms[m * LDAB + kc] = pm;
        }
        // stage W pair transposed: [n][k], 128 n x 32 k; thread covers 16 k
        {
            int nn = tid & 127, kh = (tid >> 7) * 16;
            const float* p1 = W1 + (size_t)(k0 + kh) * 128 + nn;
            const float* p2 = W2 + (size_t)(k0 + kh) * 128 + nn;
            float wa[16], wb[16];
            #pragma unroll
            for (int j = 0; j < 16; ++j) { wa[j] = p1[(size_t)j * 128]; wb[j] = p2[(size_t)j * 128]; }
            uint4 pk;
            pk.x = packbf2(wa[0], wa[1]);  pk.y = packbf2(wa[2], wa[3]);
            pk.z = packbf2(wa[4], wa[5]);  pk.w = packbf2(wa[6], wa[7]);
            *(uint4*)&W1s[nn * LDAB + kh] = pk;
            pk.x = packbf2(wa[8], wa[9]);  pk.y = packbf2(wa[10], wa[11]);
            pk.z = packbf2(wa[12], wa[13]); pk.w = packbf2(wa[14], wa[15]);
            *(uint4*)&W1s[nn * LDAB + kh + 8] = pk;
            pk.x = packbf2(wb[0], wb[1]);  pk.y = packbf2(wb[2], wb[3]);
            pk.z = packbf2(wb[4], wb[5]);  pk.w = packbf2(wb[6], wb[7]);
            *(uint4*)&W2s[nn * LDAB + kh] = pk;
            pk.x = packbf2(wb[8], wb[9]);  pk.y = packbf2(wb[10], wb[11]);
            pk.z = packbf2(wb[12], wb[13]); pk.w = packbf2(wb[14], wb[15]);
            *(uint4*)&W2s[nn * LDAB + kh + 8] = pk;
        }
        __syncthreads();
        bf16x8 au[2], am[2], bf1[4], bf2[4];
        #pragma unroll
        for (int mi = 0; mi < 2; ++mi) {
            au[mi] = *(bf16x8*)&Us[(wm * 32 + mi * 16 + lm) * LDAB + quad * 8];
            am[mi] = *(bf16x8*)&Ms[(wm * 32 + mi * 16 + lm) * LDAB + quad * 8];
        }
        #pragma unroll
        for (int ni = 0; ni < 4; ++ni) {
            bf1[ni] = *(bf16x8*)&W1s[(wn * 64 + ni * 16 + lm) * LDAB + quad * 8];
            bf2[ni] = *(bf16x8*)&W2s[(wn * 64 + ni * 16 + lm) * LDAB + quad * 8];
        }
        #pragma unroll
        for (int mi = 0; mi < 2; ++mi)
            #pragma unroll
            for (int ni = 0; ni < 4; ++ni) {
                acc1[mi][ni] = __builtin_amdgcn_mfma_f32_16x16x32_bf16(
                    au[mi], bf1[ni], acc1[mi][ni], 0, 0, 0);
                acc2[mi][ni] = __builtin_amdgcn_mfma_f32_16x16x32_bf16(
                    am[mi], bf2[ni], acc2[mi][ni], 0, 0, 0);
            }
        __syncthreads();
    }
    #pragma unroll
    for (int mi = 0; mi < 2; ++mi) {
        #pragma unroll
        for (int r = 0; r < 4; ++r) {
            int row = bm + wm * 32 + mi * 16 + quad * 4 + r;
            if (row < M) {
                #pragma unroll
                for (int ni = 0; ni < 4; ++ni) {
                    int col = wn * 64 + ni * 16 + lm;
                    float v1 = acc1[mi][ni][r] + b1[col];
                    v1 = v1 > 0.f ? v1 : 0.01f * v1;
                    float v2 = acc2[mi][ni][r] + b2[col];
                    v2 = v2 > 0.f ? v2 : 0.01f * v2;
                    out[(size_t)row * 128 + col] = v1 + v2;
                }
            }
        }
    }
}

// ---------------------------------------------------------------------------
// Fused kernels. Blocks [0, encN) do encoder work; the rest do side work.
// ---------------------------------------------------------------------------

// Q/K/V + prologue (side zeroing + ego->bf16), stage 1 only.
__global__ __launch_bounds__(256) void qkv2_pre(
    const float* __restrict__ A,
    const float* __restrict__ wq, const float* __restrict__ wk, const float* __restrict__ wv,
    const float* __restrict__ bq, const float* __restrict__ bk, const float* __restrict__ bv,
    float* __restrict__ Q, float* __restrict__ Ko, float* __restrict__ V, int M, int encGy,
    float* __restrict__ side, int Nn,
    const float* __restrict__ ego, unsigned int* __restrict__ egob,
    int encN, int ZB, int CB)
{
    __shared__ unsigned short As[64 * LDAB];
    __shared__ unsigned short Bs[128 * LDAB];
    __shared__ float redS[128], redSS[128];
    int gid = blockIdx.x;
    int tid = threadIdx.x;
    if (gid >= encN) {
        int j = gid - encN;
        if (j < ZB) {
            // zero side: Nn*128 floats = Nn*32 float4
            size_t n4 = (size_t)Nn * 32;
            float4 z = make_float4(0.f, 0.f, 0.f, 0.f);
            for (size_t i = (size_t)j * 256 + tid; i < n4; i += (size_t)ZB * 256)
                ((float4*)side)[i] = z;
        } else {
            // ego -> bf16
            int c = j - ZB;
            size_t n4 = (size_t)Nn * 32;
            for (size_t i = (size_t)c * 256 + tid; i < n4; i += (size_t)CB * 256) {
                float4 a = *(const float4*)(ego + i * 4);
                uint2 p;
                p.x = packbf2(a.x, a.y);
                p.y = packbf2(a.z, a.w);
                *(uint2*)(egob + i * 2) = p;
            }
        }
        return;
    }
    int sel = gid / encGy, by = gid % encGy;
    const float* W = (sel == 0) ? wq : (sel == 1) ? wk : wv;
    const float* b = (sel == 0) ? bq : (sel == 1) ? bk : bv;
    float* C = (sel == 0) ? Q : (sel == 1) ? Ko : V;
    gemm2_core(A, W, b, nullptr, nullptr, nullptr, C, M, 128, 128, 0,
               by * 64, 0, As, Bs, redS, redSS);
}

// Q/K/V + spmm chunk
__global__ __launch_bounds__(256) void qkv2_spmm(
    const float* __restrict__ A,
    const float* __restrict__ wq, const float* __restrict__ wk, const float* __restrict__ wv,
    const float* __restrict__ bq, const float* __restrict__ bk, const float* __restrict__ bv,
    float* __restrict__ Q, float* __restrict__ Ko, float* __restrict__ V, int M, int encGy,
    const unsigned int* __restrict__ egob, const float* __restrict__ vals,
    const int* __restrict__ rows, const int* __restrict__ cols,
    float* __restrict__ side, int nnz, int spmmBase, int encN)
{
    __shared__ unsigned short As[64 * LDAB];
    __shared__ unsigned short Bs[128 * LDAB];
    __shared__ float redS[128], redSS[128];
    int gid = blockIdx.x;
    if (gid >= encN) {
        spmm_block(egob, vals, rows, cols, side, nnz, spmmBase + gid - encN);
        return;
    }
    int sel = gid / encGy, by = gid % encGy;
    const float* W = (sel == 0) ? wq : (sel == 1) ? wk : wv;
    const float* b = (sel == 0) ? bq : (sel == 1) ? bk : bv;
    float* C = (sel == 0) ? Q : (sel == 1) ? Ko : V;
    gemm2_core(A, W, b, nullptr, nullptr, nullptr, C, M, 128, 128, 0,
               by * 64, 0, As, Bs, redS, redSS);
}

// generic GEMM (+LN) + spmm chunk
__global__ __launch_bounds__(256) void gemm2_spmm(
    const float* __restrict__ A, const float* __restrict__ W,
    const float* __restrict__ bias, const float* __restrict__ R,
    const float* __restrict__ g, const float* __restrict__ bta,
    float* __restrict__ C, int M, int N, int K, int act, int encGy,
    const unsigned int* __restrict__ egob, const float* __restrict__ vals,
    const int* __restrict__ rows, const int* __restrict__ cols,
    float* __restrict__ side, int nnz, int spmmBase, int encN)
{
    __shared__ unsigned short As[64 * LDAB];
    __shared__ unsigned short Bs[128 * LDAB];
    __shared__ float redS[128], redSS[128];
    int gid = blockIdx.x;
    if (gid >= encN) {
        spmm_block(egob, vals, rows, cols, side, nnz, spmmBase + gid - encN);
        return;
    }
    int bx = gid / encGy, by = gid % encGy;
    gemm2_core(A, W, bias, R, g, bta, C, M, N, K, act,
               by * 64, bx * 128, As, Bs, redS, redSS);
}

// generic GEMM (+LN) + bi-interaction tiles (BM=64 full-width)
__global__ __launch_bounds__(256) void gemm2_bi2(
    const float* __restrict__ A, const float* __restrict__ W,
    const float* __restrict__ bias, const float* __restrict__ R,
    const float* __restrict__ g, const float* __restrict__ bta,
    float* __restrict__ C, int M, int N, int K, int act, int encGy, int encN,
    const float* __restrict__ ego, const float* __restrict__ side,
    const float* __restrict__ W1, const float* __restrict__ b1,
    const float* __restrict__ W2, const float* __restrict__ b2,
    float* __restrict__ out, int Mbi, int biBase)
{
    __shared__ char smem[30720];   // max(gemm2 16384, bi 30720)
    int gid = blockIdx.x;
    if (gid < encN) {
        unsigned short* As = (unsigned short*)smem;
        unsigned short* Bs = (unsigned short*)(smem + 5120);
        float* redS  = (float*)(smem + 15360);
        float* redSS = (float*)(smem + 15360 + 512);
        int bx = gid / encGy, by = gid % encGy;
        gemm2_core(A, W, bias, R, g, bta, C, M, N, K, act,
                   by * 64, bx * 128, As, Bs, redS, redSS);
    } else {
        int bb = biBase + (gid - encN);
        unsigned short* Us  = (unsigned short*)smem;
        unsigned short* Ms  = (unsigned short*)(smem + 5120);
        unsigned short* W1s = (unsigned short*)(smem + 10240);
        unsigned short* W2s = (unsigned short*)(smem + 20480);
        bi_core2(ego, side, W1, b1, W2, b2, out, Mbi, bb * 64, Us, Ms, W1s, W2s);
    }
}

// Attention body (device fn): 256 threads = 256 queries of one (b,h); K/V
// staged per 128-row chunk. Online softmax.
__device__ __forceinline__ void attn_block(
    const float* __restrict__ q, const float* __restrict__ k,
    const float* __restrict__ v, float* __restrict__ o, int NH,
    int bh, float* Ks, float* Vs)
{
    const int L = 256, DK = 16;
    int b = bh / NH, h = bh % NH;
    int tid = threadIdx.x;

    size_t qbase = ((size_t)(b * L + tid) * NH + h) * DK;
    float qr[16];
    #pragma unroll
    for (int d4 = 0; d4 < 4; ++d4) {
        float4 t = *(const float4*)(q + qbase + d4 * 4);
        qr[d4*4+0] = t.x * 0.25f; qr[d4*4+1] = t.y * 0.25f;
        qr[d4*4+2] = t.z * 0.25f; qr[d4*4+3] = t.w * 0.25f;
    }
    float acc[16];
    #pragma unroll
    for (int d = 0; d < 16; ++d) acc[d] = 0.f;
    float mmax = -1e30f, ssum = 0.f;

    for (int c0 = 0; c0 < L; c0 += 128) {
        __syncthreads();
        for (int i = tid; i < 128 * 4; i += 256) {
            int ll = i >> 2, d4 = (i & 3) * 4;
            size_t gg = ((size_t)(b * L + c0 + ll) * NH + h) * DK + d4;
            *(float4*)&Ks[ll * 16 + d4] = *(const float4*)(k + gg);
            *(float4*)&Vs[ll * 16 + d4] = *(const float4*)(v + gg);
        }
        __syncthreads();

        for (int kk = 0; kk < 128; ++kk) {
            float dot = 0.f;
            #pragma unroll
            for (int d4 = 0; d4 < 4; ++d4) {
                float4 kv = *(const float4*)&Ks[kk * 16 + d4 * 4];
                dot = fmaf(qr[d4*4+0], kv.x, dot);
                dot = fmaf(qr[d4*4+1], kv.y, dot);
                dot = fmaf(qr[d4*4+2], kv.z, dot);
                dot = fmaf(qr[d4*4+3], kv.w, dot);
            }
            if (dot > mmax) {
                float alpha = __expf(mmax - dot);
                ssum *= alpha;
                #pragma unroll
                for (int d = 0; d < 16; ++d) acc[d] *= alpha;
                mmax = dot;
            }
            float p = __expf(dot - mmax);
            ssum += p;
            #pragma unroll
            for (int d4 = 0; d4 < 4; ++d4) {
                float4 vv = *(const float4*)&Vs[kk * 16 + d4 * 4];
                acc[d4*4+0] = fmaf(p, vv.x, acc[d4*4+0]);
                acc[d4*4+1] = fmaf(p, vv.y, acc[d4*4+1]);
                acc[d4*4+2] = fmaf(p, vv.z, acc[d4*4+2]);
                acc[d4*4+3] = fmaf(p, vv.w, acc[d4*4+3]);
            }
        }
    }
    float inv = 1.f / ssum;
    #pragma unroll
    for (int d4 = 0; d4 < 4; ++d4) {
        float4 t;
        t.x = acc[d4*4+0] * inv; t.y = acc[d4*4+1] * inv;
        t.z = acc[d4*4+2] * inv; t.w = acc[d4*4+3] * inv;
        *(float4*)(o + qbase + d4 * 4) = t;
    }
}

// Attention + spmm chunk
__global__ __launch_bounds__(256) void attn_spmm(
    const float* __restrict__ q, const float* __restrict__ k,
    const float* __restrict__ v, float* __restrict__ o, int NH,
    const unsigned int* __restrict__ egob, const float* __restrict__ vals,
    const int* __restrict__ rows, const int* __restrict__ cols,
    float* __restrict__ side, int nnz, int spmmBase, int encN)
{
    __shared__ float Ks[128 * 16];
    __shared__ float Vs[128 * 16];
    int gid = blockIdx.x;
    if (gid >= encN) {
        spmm_block(egob, vals, rows, cols, side, nnz, spmmBase + gid - encN);
        return;
    }
    attn_block(q, k, v, o, NH, gid, Ks, Vs);
}

// Attention + bi-interaction tiles
__global__ __launch_bounds__(256) void attn_bi(
    const float* __restrict__ q, const float* __restrict__ k,
    const float* __restrict__ v, float* __restrict__ o, int NH, int encN,
    const float* __restrict__ ego, const float* __restrict__ side,
    const float* __restrict__ W1, const float* __restrict__ b1,
    const float* __restrict__ W2, const float* __restrict__ b2,
    float* __restrict__ out, int Mbi, int biBase)
{
    __shared__ char smem[30720];   // max(attn 16384, bi 30720)
    int gid = blockIdx.x;
    if (gid < encN) {
        float* Ks = (float*)smem;
        float* Vs = (float*)(smem + 8192);
        attn_block(q, k, v, o, NH, gid, Ks, Vs);
    } else {
        int bb = biBase + (gid - encN);
        unsigned short* Us  = (unsigned short*)smem;
        unsigned short* Ms  = (unsigned short*)(smem + 5120);
        unsigned short* W1s = (unsigned short*)(smem + 10240);
        unsigned short* W2s = (unsigned short*)(smem + 20480);
        bi_core2(ego, side, W1, b1, W2, b2, out, Mbi, bb * 64, Us, Ms, W1s, W2s);
    }
}

extern "C" void kernel_launch(void* const* d_in, const int* in_sizes, int n_in,
                              void* d_out, int out_size, void* d_ws, size_t ws_size,
                              hipStream_t stream) {
    const float* ego    = (const float*)d_in[0];
    const float* vals   = (const float*)d_in[1];
    const float* W1     = (const float*)d_in[2];
    const float* b1     = (const float*)d_in[3];
    const float* W2     = (const float*)d_in[4];
    const float* b2     = (const float*)d_in[5];
    const float* enc_in = (const float*)d_in[6];
    const float* wq  = (const float*)d_in[7];
    const float* bq  = (const float*)d_in[8];
    const float* wk  = (const float*)d_in[9];
    const float* bk  = (const float*)d_in[10];
    const float* wv  = (const float*)d_in[11];
    const float* bv  = (const float*)d_in[12];
    const float* wo  = (const float*)d_in[13];
    const float* bo  = (const float*)d_in[14];
    const float* ln1_g = (const float*)d_in[15];
    const float* ln1_b = (const float*)d_in[16];
    const float* cw1 = (const float*)d_in[17];
    const float* cb1 = (const float*)d_in[18];
    const float* cw2 = (const float*)d_in[19];
    const float* cb2 = (const float*)d_in[20];
    const float* ln2_g = (const float*)d_in[21];
    const float* ln2_b = (const float*)d_in[22];
    const int* rows = (const int*)d_in[23];
    const int* cols = (const int*)d_in[24];

    const int D = 128, DI = 512, NH = 8, L = 256;
    const int Nn   = in_sizes[0] / D;        // 100000
    const int nnz  = in_sizes[1];            // 2000000
    const int NL   = in_sizes[7] / (D * D);  // 2
    const int Menc = in_sizes[6] / D;        // 8192 (= B*L)
    const int Bb   = Menc / L;               // 32

    float* ws = (float*)d_ws;
    size_t off = 0;
    float* side = ws + off; off += (size_t)Nn * D;
    float* Qb = ws + off; off += (size_t)Menc * D;
    float* Kb = ws + off; off += (size_t)Menc * D;
    float* Vb = ws + off; off += (size_t)Menc * D;
    float* Ob = ws + off; off += (size_t)Menc * D;
    float* XA = ws + off; off += (size_t)Menc * D;
    float* XB = ws + off; off += (size_t)Menc * D;
    float* Hb = ws + off; off += (size_t)Menc * DI;
    unsigned int* egob = (unsigned int*)(ws + off); off += (size_t)Nn * (D / 2); // bf16 ego

    float* outAgg = (float*)d_out;
    float* outX   = (float*)d_out + (size_t)Nn * D;

    // ---- fused schedule over 5*NL stages:
    //   stage 1:            prologue roles (zero side + ego->bf16)
    //   stages 2..5NL-4:    spmm chunks
    //   last 4 stages:      bi-interaction tiles (need spmm complete)
    const int spmmBlocks = (nnz + 255) / 256;
    const int nSpmmStages = 5 * NL - 5;
    const int perS = (spmmBlocks + nSpmmStages - 1) / nSpmmStages;
    const int biTiles = (Nn + 63) / 64;
    const int perB = (biTiles + 3) / 4;
    const int biStart = 5 * NL - 3;          // first bi stage index
    const int encGy = Menc / 64;
    const int ZB = 512, CB = 1024;
    int sidx = 0, sci = 0, bci = 0;

    const float* x = enc_in;
    for (int i = 0; i < NL; ++i) {
        const size_t wOff = (size_t)i * D * D;
        int base, cnt;
        #define SPMM_CHUNK base = sci * perS; cnt = spmmBlocks - base; \
                           if (cnt < 0) cnt = 0; if (cnt > perS) cnt = perS; sci++
        #define BI_CHUNK   base = bci * perB; cnt = biTiles - base; \
                           if (cnt < 0) cnt = 0; if (cnt > perB) cnt = perB; bci++

        // --- Q/K/V projection ---
        sidx++;
        if (sidx == 1) {
            qkv2_pre<<<3 * encGy + ZB + CB, 256, 0, stream>>>(
                x, wq + wOff, wk + wOff, wv + wOff,
                bq + (size_t)i * D, bk + (size_t)i * D, bv + (size_t)i * D,
                Qb, Kb, Vb, Menc, encGy,
                side, Nn, ego, egob, 3 * encGy, ZB, CB);
        } else {
            SPMM_CHUNK;
            qkv2_spmm<<<3 * encGy + cnt, 256, 0, stream>>>(
                x, wq + wOff, wk + wOff, wv + wOff,
                bq + (size_t)i * D, bk + (size_t)i * D, bv + (size_t)i * D,
                Qb, Kb, Vb, Menc, encGy,
                egob, vals, rows, cols, side, nnz, base, 3 * encGy);
        }

        // --- attention ---
        sidx++;
        if (sidx >= biStart) {
            BI_CHUNK;
            attn_bi<<<Bb * NH + cnt, 256, 0, stream>>>(
                Qb, Kb, Vb, Ob, NH, Bb * NH,
                ego, side, W1, b1, W2, b2, outAgg, Nn, base);
        } else {
            SPMM_CHUNK;
            attn_spmm<<<Bb * NH + cnt, 256, 0, stream>>>(
                Qb, Kb, Vb, Ob, NH,
                egob, vals, rows, cols, side, nnz, base, Bb * NH);
        }

        // --- MHA out-proj + residual + LN1 ---
        sidx++;
        if (sidx >= biStart) {
            BI_CHUNK;
            gemm2_bi2<<<encGy + cnt, 256, 0, stream>>>(
                Ob, wo + wOff, bo + (size_t)i * D, x,
                ln1_g + (size_t)i * D, ln1_b + (size_t)i * D, XA, Menc, D, D, 0,
                encGy, encGy,
                ego, side, W1, b1, W2, b2, outAgg, Nn, base);
        } else {
            SPMM_CHUNK;
            gemm2_spmm<<<encGy + cnt, 256, 0, stream>>>(
                Ob, wo + wOff, bo + (size_t)i * D, x,
                ln1_g + (size_t)i * D, ln1_b + (size_t)i * D, XA, Menc, D, D, 0, encGy,
                egob, vals, rows, cols, side, nnz, base, encGy);
        }

        // --- FFN up + relu ---
        sidx++;
        if (sidx >= biStart) {
            BI_CHUNK;
            gemm2_bi2<<<4 * encGy + cnt, 256, 0, stream>>>(
                XA, cw1 + (size_t)i * D * DI, cb1 + (size_t)i * DI, nullptr,
                nullptr, nullptr, Hb, Menc, DI, D, 1, encGy, 4 * encGy,
                ego, side, W1, b1, W2, b2, outAgg, Nn, base);
        } else {
            SPMM_CHUNK;
            gemm2_spmm<<<4 * encGy + cnt, 256, 0, stream>>>(
                XA, cw1 + (size_t)i * D * DI, cb1 + (size_t)i * DI, nullptr,
                nullptr, nullptr, Hb, Menc, DI, D, 1, encGy,
                egob, vals, rows, cols, side, nnz, base, 4 * encGy);
        }

        // --- FFN down + residual + LN2 ---
        sidx++;
        float* dst = (i == NL - 1) ? outX : XB;
        if (sidx >= biStart) {
            BI_CHUNK;
            gemm2_bi2<<<encGy + cnt, 256, 0, stream>>>(
                Hb, cw2 + (size_t)i * DI * D, cb2 + (size_t)i * D, XA,
                ln2_g + (size_t)i * D, ln2_b + (size_t)i * D, dst, Menc, D, DI, 0,
                encGy, encGy,
                ego, side, W1, b1, W2, b2, outAgg, Nn, base);
        } else {
            SPMM_CHUNK;
            gemm2_spmm<<<encGy + cnt, 256, 0, stream>>>(
                Hb, cw2 + (size_t)i * DI * D, cb2 + (size_t)i * D, XA,
                ln2_g + (size_t)i * D, ln2_b + (size_t)i * D, dst, Menc, D, DI, 0, encGy,
                egob, vals, rows, cols, side, nnz, base, encGy);
        }
        #undef SPMM_CHUNK
        #undef BI_CHUNK
        x = XB;
    }
}

// Round 7
// 475.632 us; speedup vs baseline: 1.0558x; 1.0558x over previous
//
#include <hip/hip_runtime.h>

typedef __attribute__((ext_vector_type(8))) short bf16x8;
typedef __attribute__((ext_vector_type(4))) float f32x4;

__device__ __forceinline__ unsigned short f2b(float f) {
    union { float f; unsigned int i; } u; u.f = f;
    return (unsigned short)((u.i + 0x7FFFu + ((u.i >> 16) & 1u)) >> 16);
}
__device__ __forceinline__ unsigned int packbf2(float a, float b) {
    return (unsigned int)f2b(a) | ((unsigned int)f2b(b) << 16);
}

// ---------------------------------------------------------------------------
// SpMM block (device fn): side[r,:] += vals[e] * ego_bf16[cols[e],:]
// (rows sorted). 256 edges per call (4 waves x 64). Metadata via v_readlane;
// row transition = scalar branch; depth-16 register prefetch queue.
// Order-independent across blocks (atomics).
// ---------------------------------------------------------------------------
__device__ __forceinline__ void spmm_block(
    const unsigned int* __restrict__ egob, const float* __restrict__ vals,
    const int* __restrict__ rows, const int* __restrict__ cols,
    float* __restrict__ side, int nnz, int blk)
{
    int tid = threadIdx.x;
    int wave = tid >> 6, lane = tid & 63;
    int e0 = blk * 256 + wave * 64;
    if (e0 >= nnz) return;

    int idx = e0 + lane;
    int last = nnz - 1;
    bool ok = idx < nnz;
    int safe = ok ? idx : last;
    int my_row = rows[safe];
    int my_col = cols[safe];
    float my_val = ok ? vals[safe] : 0.f;

    unsigned int pre[16];
    #pragma unroll
    for (int j = 0; j < 16; ++j) {
        unsigned int c = (unsigned int)__builtin_amdgcn_readlane(my_col, j);
        pre[j] = *(egob + ((size_t)c << 6) + lane);
    }

    float ax = 0.f, ay = 0.f;
    int cur = __builtin_amdgcn_readlane(my_row, 0);
    #pragma unroll
    for (int e = 0; e < 64; ++e) {
        int r = __builtin_amdgcn_readlane(my_row, e);
        float vv = __int_as_float(__builtin_amdgcn_readlane(__float_as_int(my_val), e));
        unsigned int u = pre[e & 15];
        if (e < 48) {
            unsigned int c = (unsigned int)__builtin_amdgcn_readlane(my_col, e + 16);
            pre[e & 15] = *(egob + ((size_t)c << 6) + lane);
        }
        if (r != cur) {
            atomicAdd(&side[(size_t)cur * 128 + lane * 2], ax);
            atomicAdd(&side[(size_t)cur * 128 + lane * 2 + 1], ay);
            ax = 0.f; ay = 0.f; cur = r;
        }
        ax = fmaf(vv, __uint_as_float(u << 16), ax);
        ay = fmaf(vv, __uint_as_float(u & 0xFFFF0000u), ay);
    }
    atomicAdd(&side[(size_t)cur * 128 + lane * 2], ax);
    atomicAdd(&side[(size_t)cur * 128 + lane * 2 + 1], ay);
}

#define LDAB 40   // bf16 row stride in LDS (80B rows -> 2-way conflicts only)

// ---------------------------------------------------------------------------
// gemm2 core: BM=64 x BN=128 tile, 256 threads = 4 waves as 2(m) x 2(n).
// C = act(A@W + bias [+R]) with optional fused row-LayerNorm (g,bta; N==128).
// ---------------------------------------------------------------------------
__device__ __forceinline__ void gemm2_core(
    const float* __restrict__ A, const float* __restrict__ W,
    const float* __restrict__ bias, const float* __restrict__ R,
    const float* __restrict__ g, const float* __restrict__ bta,
    float* __restrict__ C, int M, int N, int K, int act,
    int bm, int bn, unsigned short* As, unsigned short* Bs,
    float* redS, float* redSS)
{
    int tid = threadIdx.x, wave = tid >> 6, lane = tid & 63;
    int lm = lane & 15, quad = lane >> 4;
    int wm = wave >> 1, wn = wave & 1;

    f32x4 acc[2][4];
    #pragma unroll
    for (int i = 0; i < 2; ++i)
        #pragma unroll
        for (int j = 0; j < 4; ++j) acc[i][j] = (f32x4)(0.f);

    for (int k0 = 0; k0 < K; k0 += 32) {
        {
            int m = tid >> 2, kc = (tid & 3) * 8;
            const float* p = A + (size_t)(bm + m) * K + k0 + kc;
            float4 a0 = *(const float4*)p, a1 = *(const float4*)(p + 4);
            uint4 pk;
            pk.x = packbf2(a0.x, a0.y); pk.y = packbf2(a0.z, a0.w);
            pk.z = packbf2(a1.x, a1.y); pk.w = packbf2(a1.z, a1.w);
            *(uint4*)&As[m * LDAB + kc] = pk;
        }
        {
            int nn = tid & 127, kh = (tid >> 7) * 16;
            const float* p = W + (size_t)(k0 + kh) * N + bn + nn;
            float w[16];
            #pragma unroll
            for (int j = 0; j < 16; ++j) w[j] = p[(size_t)j * N];
            uint4 pk;
            pk.x = packbf2(w[0], w[1]);  pk.y = packbf2(w[2], w[3]);
            pk.z = packbf2(w[4], w[5]);  pk.w = packbf2(w[6], w[7]);
            *(uint4*)&Bs[nn * LDAB + kh] = pk;
            pk.x = packbf2(w[8], w[9]);  pk.y = packbf2(w[10], w[11]);
            pk.z = packbf2(w[12], w[13]); pk.w = packbf2(w[14], w[15]);
            *(uint4*)&Bs[nn * LDAB + kh + 8] = pk;
        }
        __syncthreads();
        bf16x8 af[2], bfr[4];
        #pragma unroll
        for (int mi = 0; mi < 2; ++mi)
            af[mi] = *(bf16x8*)&As[(wm * 32 + mi * 16 + lm) * LDAB + quad * 8];
        #pragma unroll
        for (int ni = 0; ni < 4; ++ni)
            bfr[ni] = *(bf16x8*)&Bs[(wn * 64 + ni * 16 + lm) * LDAB + quad * 8];
        #pragma unroll
        for (int mi = 0; mi < 2; ++mi)
            #pragma unroll
            for (int ni = 0; ni < 4; ++ni)
                acc[mi][ni] = __builtin_amdgcn_mfma_f32_16x16x32_bf16(
                    af[mi], bfr[ni], acc[mi][ni], 0, 0, 0);
        __syncthreads();
    }

    #pragma unroll
    for (int mi = 0; mi < 2; ++mi) {
        #pragma unroll
        for (int r = 0; r < 4; ++r) {
            int row = bm + wm * 32 + mi * 16 + quad * 4 + r;
            #pragma unroll
            for (int ni = 0; ni < 4; ++ni) {
                int col = bn + wn * 64 + ni * 16 + lm;
                float v = acc[mi][ni][r] + bias[col];
                if (R) v += R[(size_t)row * N + col];
                if (act) v = fmaxf(v, 0.f);
                acc[mi][ni][r] = v;
            }
        }
    }

    if (g) {
        #pragma unroll
        for (int mi = 0; mi < 2; ++mi) {
            #pragma unroll
            for (int r = 0; r < 4; ++r) {
                float s = 0.f, ss = 0.f;
                #pragma unroll
                for (int ni = 0; ni < 4; ++ni) {
                    float v = acc[mi][ni][r];
                    s += v; ss = fmaf(v, v, ss);
                }
                #pragma unroll
                for (int off = 1; off < 16; off <<= 1) {
                    s  += __shfl_xor(s, off, 64);
                    ss += __shfl_xor(ss, off, 64);
                }
                if (lm == 0) {
                    int lr = wm * 32 + mi * 16 + quad * 4 + r;
                    redS[wn * 64 + lr] = s;
                    redSS[wn * 64 + lr] = ss;
                }
            }
        }
        __syncthreads();
        #pragma unroll
        for (int mi = 0; mi < 2; ++mi) {
            #pragma unroll
            for (int r = 0; r < 4; ++r) {
                int lr = wm * 32 + mi * 16 + quad * 4 + r;
                int row = bm + lr;
                float s = redS[lr] + redS[64 + lr];
                float ss = redSS[lr] + redSS[64 + lr];
                float mean = s * (1.f / 128.f);
                float var = ss * (1.f / 128.f) - mean * mean;
                float rstd = rsqrtf(var + 1e-5f);
                #pragma unroll
                for (int ni = 0; ni < 4; ++ni) {
                    int col = wn * 64 + ni * 16 + lm;
                    float y = (acc[mi][ni][r] - mean) * rstd * g[col] + bta[col];
                    C[(size_t)row * 128 + col] = y;
                }
            }
        }
    } else {
        #pragma unroll
        for (int mi = 0; mi < 2; ++mi) {
            #pragma unroll
            for (int r = 0; r < 4; ++r) {
                int row = bm + wm * 32 + mi * 16 + quad * 4 + r;
                #pragma unroll
                for (int ni = 0; ni < 4; ++ni) {
                    int col = bn + wn * 64 + ni * 16 + lm;
                    C[(size_t)row * N + col] = acc[mi][ni][r];
                }
            }
        }
    }
}

// ---------------------------------------------------------------------------
// Bi-interaction core v2: BM=64 x BN=128 (full width -> each row panel staged
// ONCE). out = leaky((ego+side)@W1+b1) + leaky((ego*side)@W2+b2), K=N=128.
// 4 waves as 2(m) x 2(n). LDS: Us/Ms 64xLDAB + W1s/W2s 128xLDAB = 30720 B.
// ---------------------------------------------------------------------------
__device__ __forceinline__ void bi_core2(
    const float* __restrict__ ego, const float* __restrict__ side,
    const float* __restrict__ W1, const float* __restrict__ b1,
    const float* __restrict__ W2, const float* __restrict__ b2,
    float* __restrict__ out, int M, int bm,
    unsigned short* Us, unsigned short* Ms,
    unsigned short* W1s, unsigned short* W2s)
{
    int tid = threadIdx.x, wave = tid >> 6, lane = tid & 63;
    int lm = lane & 15, quad = lane >> 4;
    int wm = wave >> 1, wn = wave & 1;

    f32x4 acc1[2][4], acc2[2][4];
    #pragma unroll
    for (int i = 0; i < 2; ++i)
        #pragma unroll
        for (int j = 0; j < 4; ++j) { acc1[i][j] = (f32x4)(0.f); acc2[i][j] = (f32x4)(0.f); }

    for (int k0 = 0; k0 < 128; k0 += 32) {
        {
            int m = tid >> 2, kc = (tid & 3) * 8;
            int gm = bm + m;
            float e[8], s[8];
            if (gm < M) {
                const float* pe = ego + (size_t)gm * 128 + k0 + kc;
                const float* ps = side + (size_t)gm * 128 + k0 + kc;
                float4 e0 = *(const float4*)pe, e1 = *(const float4*)(pe + 4);
                float4 s0 = *(const float4*)ps, s1 = *(const float4*)(ps + 4);
                e[0]=e0.x; e[1]=e0.y; e[2]=e0.z; e[3]=e0.w;
                e[4]=e1.x; e[5]=e1.y; e[6]=e1.z; e[7]=e1.w;
                s[0]=s0.x; s[1]=s0.y; s[2]=s0.z; s[3]=s0.w;
                s[4]=s1.x; s[5]=s1.y; s[6]=s1.z; s[7]=s1.w;
            } else {
                #pragma unroll
                for (int j = 0; j < 8; ++j) { e[j] = 0.f; s[j] = 0.f; }
            }
            uint4 pu, pm;
            pu.x = packbf2(e[0]+s[0], e[1]+s[1]); pu.y = packbf2(e[2]+s[2], e[3]+s[3]);
            pu.z = packbf2(e[4]+s[4], e[5]+s[5]); pu.w = packbf2(e[6]+s[6], e[7]+s[7]);
            pm.x = packbf2(e[0]*s[0], e[1]*s[1]); pm.y = packbf2(e[2]*s[2], e[3]*s[3]);
            pm.z = packbf2(e[4]*s[4], e[5]*s[5]); pm.w = packbf2(e[6]*s[6], e[7]*s[7]);
            *(uint4*)&Us[m * LDAB + kc] = pu;
            *(uint4*)&Ms[m * LDAB + kc] = pm;
        }
        {
            int nn = tid & 127, kh = (tid >> 7) * 16;
            const float* p1 = W1 + (size_t)(k0 + kh) * 128 + nn;
            const float* p2 = W2 + (size_t)(k0 + kh) * 128 + nn;
            float wa[16], wb[16];
            #pragma unroll
            for (int j = 0; j < 16; ++j) { wa[j] = p1[(size_t)j * 128]; wb[j] = p2[(size_t)j * 128]; }
            uint4 pk;
            pk.x = packbf2(wa[0], wa[1]);  pk.y = packbf2(wa[2], wa[3]);
            pk.z = packbf2(wa[4], wa[5]);  pk.w = packbf2(wa[6], wa[7]);
            *(uint4*)&W1s[nn * LDAB + kh] = pk;
            pk.x = packbf2(wa[8], wa[9]);  pk.y = packbf2(wa[10], wa[11]);
            pk.z = packbf2(wa[12], wa[13]); pk.w = packbf2(wa[14], wa[15]);
            *(uint4*)&W1s[nn * LDAB + kh + 8] = pk;
            pk.x = packbf2(wb[0], wb[1]);  pk.y = packbf2(wb[2], wb[3]);
            pk.z = packbf2(wb[4], wb[5]);  pk.w = packbf2(wb[6], wb[7]);
            *(uint4*)&W2s[nn * LDAB + kh] = pk;
            pk.x = packbf2(wb[8], wb[9]);  pk.y = packbf2(wb[10], wb[11]);
            pk.z = packbf2(wb[12], wb[13]); pk.w = packbf2(wb[14], wb[15]);
            *(uint4*)&W2s[nn * LDAB + kh + 8] = pk;
        }
        __syncthreads();
        bf16x8 au[2], am[2], bf1[4], bf2[4];
        #pragma unroll
        for (int mi = 0; mi < 2; ++mi) {
            au[mi] = *(bf16x8*)&Us[(wm * 32 + mi * 16 + lm) * LDAB + quad * 8];
            am[mi] = *(bf16x8*)&Ms[(wm * 32 + mi * 16 + lm) * LDAB + quad * 8];
        }
        #pragma unroll
        for (int ni = 0; ni < 4; ++ni) {
            bf1[ni] = *(bf16x8*)&W1s[(wn * 64 + ni * 16 + lm) * LDAB + quad * 8];
            bf2[ni] = *(bf16x8*)&W2s[(wn * 64 + ni * 16 + lm) * LDAB + quad * 8];
        }
        #pragma unroll
        for (int mi = 0; mi < 2; ++mi)
            #pragma unroll
            for (int ni = 0; ni < 4; ++ni) {
                acc1[mi][ni] = __builtin_amdgcn_mfma_f32_16x16x32_bf16(
                    au[mi], bf1[ni], acc1[mi][ni], 0, 0, 0);
                acc2[mi][ni] = __builtin_amdgcn_mfma_f32_16x16x32_bf16(
                    am[mi], bf2[ni], acc2[mi][ni], 0, 0, 0);
            }
        __syncthreads();
    }
    #pragma unroll
    for (int mi = 0; mi < 2; ++mi) {
        #pragma unroll
        for (int r = 0; r < 4; ++r) {
            int row = bm + wm * 32 + mi * 16 + quad * 4 + r;
            if (row < M) {
                #pragma unroll
                for (int ni = 0; ni < 4; ++ni) {
                    int col = wn * 64 + ni * 16 + lm;
                    float v1 = acc1[mi][ni][r] + b1[col];
                    v1 = v1 > 0.f ? v1 : 0.01f * v1;
                    float v2 = acc2[mi][ni][r] + b2[col];
                    v2 = v2 > 0.f ? v2 : 0.01f * v2;
                    out[(size_t)row * 128 + col] = v1 + v2;
                }
            }
        }
    }
}

// ---------------------------------------------------------------------------
// Fused kernels. Blocks [0, encN) do encoder work; the rest do side work.
// ---------------------------------------------------------------------------

// Q/K/V + prologue (side zeroing + ego->bf16), stage 1 only.
__global__ __launch_bounds__(256) void qkv2_pre(
    const float* __restrict__ A,
    const float* __restrict__ wq, const float* __restrict__ wk, const float* __restrict__ wv,
    const float* __restrict__ bq, const float* __restrict__ bk, const float* __restrict__ bv,
    float* __restrict__ Q, float* __restrict__ Ko, float* __restrict__ V, int M, int encGy,
    float* __restrict__ side, int Nn,
    const float* __restrict__ ego, unsigned int* __restrict__ egob,
    int encN, int ZB, int CB)
{
    __shared__ unsigned short As[64 * LDAB];
    __shared__ unsigned short Bs[128 * LDAB];
    __shared__ float redS[128], redSS[128];
    int gid = blockIdx.x;
    int tid = threadIdx.x;
    if (gid >= encN) {
        int j = gid - encN;
        if (j < ZB) {
            size_t n4 = (size_t)Nn * 32;
            float4 z = make_float4(0.f, 0.f, 0.f, 0.f);
            for (size_t i = (size_t)j * 256 + tid; i < n4; i += (size_t)ZB * 256)
                ((float4*)side)[i] = z;
        } else {
            int c = j - ZB;
            size_t n4 = (size_t)Nn * 32;
            for (size_t i = (size_t)c * 256 + tid; i < n4; i += (size_t)CB * 256) {
                float4 a = *(const float4*)(ego + i * 4);
                uint2 p;
                p.x = packbf2(a.x, a.y);
                p.y = packbf2(a.z, a.w);
                *(uint2*)(egob + i * 2) = p;
            }
        }
        return;
    }
    int sel = gid / encGy, by = gid % encGy;
    const float* W = (sel == 0) ? wq : (sel == 1) ? wk : wv;
    const float* b = (sel == 0) ? bq : (sel == 1) ? bk : bv;
    float* C = (sel == 0) ? Q : (sel == 1) ? Ko : V;
    gemm2_core(A, W, b, nullptr, nullptr, nullptr, C, M, 128, 128, 0,
               by * 64, 0, As, Bs, redS, redSS);
}

// Q/K/V + spmm chunk
__global__ __launch_bounds__(256) void qkv2_spmm(
    const float* __restrict__ A,
    const float* __restrict__ wq, const float* __restrict__ wk, const float* __restrict__ wv,
    const float* __restrict__ bq, const float* __restrict__ bk, const float* __restrict__ bv,
    float* __restrict__ Q, float* __restrict__ Ko, float* __restrict__ V, int M, int encGy,
    const unsigned int* __restrict__ egob, const float* __restrict__ vals,
    const int* __restrict__ rows, const int* __restrict__ cols,
    float* __restrict__ side, int nnz, int spmmBase, int encN)
{
    __shared__ unsigned short As[64 * LDAB];
    __shared__ unsigned short Bs[128 * LDAB];
    __shared__ float redS[128], redSS[128];
    int gid = blockIdx.x;
    if (gid >= encN) {
        spmm_block(egob, vals, rows, cols, side, nnz, spmmBase + gid - encN);
        return;
    }
    int sel = gid / encGy, by = gid % encGy;
    const float* W = (sel == 0) ? wq : (sel == 1) ? wk : wv;
    const float* b = (sel == 0) ? bq : (sel == 1) ? bk : bv;
    float* C = (sel == 0) ? Q : (sel == 1) ? Ko : V;
    gemm2_core(A, W, b, nullptr, nullptr, nullptr, C, M, 128, 128, 0,
               by * 64, 0, As, Bs, redS, redSS);
}

// generic GEMM (+LN) + spmm chunk
__global__ __launch_bounds__(256) void gemm2_spmm(
    const float* __restrict__ A, const float* __restrict__ W,
    const float* __restrict__ bias, const float* __restrict__ R,
    const float* __restrict__ g, const float* __restrict__ bta,
    float* __restrict__ C, int M, int N, int K, int act, int encGy,
    const unsigned int* __restrict__ egob, const float* __restrict__ vals,
    const int* __restrict__ rows, const int* __restrict__ cols,
    float* __restrict__ side, int nnz, int spmmBase, int encN)
{
    __shared__ unsigned short As[64 * LDAB];
    __shared__ unsigned short Bs[128 * LDAB];
    __shared__ float redS[128], redSS[128];
    int gid = blockIdx.x;
    if (gid >= encN) {
        spmm_block(egob, vals, rows, cols, side, nnz, spmmBase + gid - encN);
        return;
    }
    int bx = gid / encGy, by = gid % encGy;
    gemm2_core(A, W, bias, R, g, bta, C, M, N, K, act,
               by * 64, bx * 128, As, Bs, redS, redSS);
}

// generic GEMM (+LN) + bi-interaction tiles (BM=64 full-width)
__global__ __launch_bounds__(256) void gemm2_bi2(
    const float* __restrict__ A, const float* __restrict__ W,
    const float* __restrict__ bias, const float* __restrict__ R,
    const float* __restrict__ g, const float* __restrict__ bta,
    float* __restrict__ C, int M, int N, int K, int act, int encGy, int encN,
    const float* __restrict__ ego, const float* __restrict__ side,
    const float* __restrict__ W1, const float* __restrict__ b1,
    const float* __restrict__ W2, const float* __restrict__ b2,
    float* __restrict__ out, int Mbi, int biBase)
{
    __shared__ char smem[30720];   // max(gemm2 16384, bi 30720)
    int gid = blockIdx.x;
    if (gid < encN) {
        unsigned short* As = (unsigned short*)smem;
        unsigned short* Bs = (unsigned short*)(smem + 5120);
        float* redS  = (float*)(smem + 15360);
        float* redSS = (float*)(smem + 15360 + 512);
        int bx = gid / encGy, by = gid % encGy;
        gemm2_core(A, W, bias, R, g, bta, C, M, N, K, act,
                   by * 64, bx * 128, As, Bs, redS, redSS);
    } else {
        int bb = biBase + (gid - encN);
        unsigned short* Us  = (unsigned short*)smem;
        unsigned short* Ms  = (unsigned short*)(smem + 5120);
        unsigned short* W1s = (unsigned short*)(smem + 10240);
        unsigned short* W2s = (unsigned short*)(smem + 20480);
        bi_core2(ego, side, W1, b1, W2, b2, out, Mbi, bb * 64, Us, Ms, W1s, W2s);
    }
}

// Attention body (device fn): 256 threads = 256 queries of one (b,h); K/V
// staged per 128-row chunk. Online softmax.
__device__ __forceinline__ void attn_block(
    const float* __restrict__ q, const float* __restrict__ k,
    const float* __restrict__ v, float* __restrict__ o, int NH,
    int bh, float* Ks, float* Vs)
{
    const int L = 256, DK = 16;
    int b = bh / NH, h = bh % NH;
    int tid = threadIdx.x;

    size_t qbase = ((size_t)(b * L + tid) * NH + h) * DK;
    float qr[16];
    #pragma unroll
    for (int d4 = 0; d4 < 4; ++d4) {
        float4 t = *(const float4*)(q + qbase + d4 * 4);
        qr[d4*4+0] = t.x * 0.25f; qr[d4*4+1] = t.y * 0.25f;
        qr[d4*4+2] = t.z * 0.25f; qr[d4*4+3] = t.w * 0.25f;
    }
    float acc[16];
    #pragma unroll
    for (int d = 0; d < 16; ++d) acc[d] = 0.f;
    float mmax = -1e30f, ssum = 0.f;

    for (int c0 = 0; c0 < L; c0 += 128) {
        __syncthreads();
        for (int i = tid; i < 128 * 4; i += 256) {
            int ll = i >> 2, d4 = (i & 3) * 4;
            size_t gg = ((size_t)(b * L + c0 + ll) * NH + h) * DK + d4;
            *(float4*)&Ks[ll * 16 + d4] = *(const float4*)(k + gg);
            *(float4*)&Vs[ll * 16 + d4] = *(const float4*)(v + gg);
        }
        __syncthreads();

        for (int kk = 0; kk < 128; ++kk) {
            float dot = 0.f;
            #pragma unroll
            for (int d4 = 0; d4 < 4; ++d4) {
                float4 kv = *(const float4*)&Ks[kk * 16 + d4 * 4];
                dot = fmaf(qr[d4*4+0], kv.x, dot);
                dot = fmaf(qr[d4*4+1], kv.y, dot);
                dot = fmaf(qr[d4*4+2], kv.z, dot);
                dot = fmaf(qr[d4*4+3], kv.w, dot);
            }
            if (dot > mmax) {
                float alpha = __expf(mmax - dot);
                ssum *= alpha;
                #pragma unroll
                for (int d = 0; d < 16; ++d) acc[d] *= alpha;
                mmax = dot;
            }
            float p = __expf(dot - mmax);
            ssum += p;
            #pragma unroll
            for (int d4 = 0; d4 < 4; ++d4) {
                float4 vv = *(const float4*)&Vs[kk * 16 + d4 * 4];
                acc[d4*4+0] = fmaf(p, vv.x, acc[d4*4+0]);
                acc[d4*4+1] = fmaf(p, vv.y, acc[d4*4+1]);
                acc[d4*4+2] = fmaf(p, vv.z, acc[d4*4+2]);
                acc[d4*4+3] = fmaf(p, vv.w, acc[d4*4+3]);
            }
        }
    }
    float inv = 1.f / ssum;
    #pragma unroll
    for (int d4 = 0; d4 < 4; ++d4) {
        float4 t;
        t.x = acc[d4*4+0] * inv; t.y = acc[d4*4+1] * inv;
        t.z = acc[d4*4+2] * inv; t.w = acc[d4*4+3] * inv;
        *(float4*)(o + qbase + d4 * 4) = t;
    }
}

// Attention + spmm chunk
__global__ __launch_bounds__(256) void attn_spmm(
    const float* __restrict__ q, const float* __restrict__ k,
    const float* __restrict__ v, float* __restrict__ o, int NH,
    const unsigned int* __restrict__ egob, const float* __restrict__ vals,
    const int* __restrict__ rows, const int* __restrict__ cols,
    float* __restrict__ side, int nnz, int spmmBase, int encN)
{
    __shared__ float Ks[128 * 16];
    __shared__ float Vs[128 * 16];
    int gid = blockIdx.x;
    if (gid >= encN) {
        spmm_block(egob, vals, rows, cols, side, nnz, spmmBase + gid - encN);
        return;
    }
    attn_block(q, k, v, o, NH, gid, Ks, Vs);
}

extern "C" void kernel_launch(void* const* d_in, const int* in_sizes, int n_in,
                              void* d_out, int out_size, void* d_ws, size_t ws_size,
                              hipStream_t stream) {
    const float* ego    = (const float*)d_in[0];
    const float* vals   = (const float*)d_in[1];
    const float* W1     = (const float*)d_in[2];
    const float* b1     = (const float*)d_in[3];
    const float* W2     = (const float*)d_in[4];
    const float* b2     = (const float*)d_in[5];
    const float* enc_in = (const float*)d_in[6];
    const float* wq  = (const float*)d_in[7];
    const float* bq  = (const float*)d_in[8];
    const float* wk  = (const float*)d_in[9];
    const float* bk  = (const float*)d_in[10];
    const float* wv  = (const float*)d_in[11];
    const float* bv  = (const float*)d_in[12];
    const float* wo  = (const float*)d_in[13];
    const float* bo  = (const float*)d_in[14];
    const float* ln1_g = (const float*)d_in[15];
    const float* ln1_b = (const float*)d_in[16];
    const float* cw1 = (const float*)d_in[17];
    const float* cb1 = (const float*)d_in[18];
    const float* cw2 = (const float*)d_in[19];
    const float* cb2 = (const float*)d_in[20];
    const float* ln2_g = (const float*)d_in[21];
    const float* ln2_b = (const float*)d_in[22];
    const int* rows = (const int*)d_in[23];
    const int* cols = (const int*)d_in[24];

    const int D = 128, DI = 512, NH = 8, L = 256;
    const int Nn   = in_sizes[0] / D;        // 100000
    const int nnz  = in_sizes[1];            // 2000000
    const int NL   = in_sizes[7] / (D * D);  // 2
    const int Menc = in_sizes[6] / D;        // 8192 (= B*L)
    const int Bb   = Menc / L;               // 32

    float* ws = (float*)d_ws;
    size_t off = 0;
    float* side = ws + off; off += (size_t)Nn * D;
    float* Qb = ws + off; off += (size_t)Menc * D;
    float* Kb = ws + off; off += (size_t)Menc * D;
    float* Vb = ws + off; off += (size_t)Menc * D;
    float* Ob = ws + off; off += (size_t)Menc * D;
    float* XA = ws + off; off += (size_t)Menc * D;
    float* XB = ws + off; off += (size_t)Menc * D;
    float* Hb = ws + off; off += (size_t)Menc * DI;
    unsigned int* egob = (unsigned int*)(ws + off); off += (size_t)Nn * (D / 2); // bf16 ego

    float* outAgg = (float*)d_out;
    float* outX   = (float*)d_out + (size_t)Nn * D;

    // ---- fused schedule over 5*NL stages:
    //   stage 1:          prologue roles (zero side + ego->bf16)
    //   stages 2..5NL-2:  spmm chunks (7 stages at NL=2 -> minimal chunk size;
    //                     R6 showed bigger chunks inflate their stage)
    //   last 2 stages:    bi-interaction tiles (need spmm complete)
    const int spmmBlocks = (nnz + 255) / 256;
    const int nSpmmStages = 5 * NL - 3;
    const int perS = (spmmBlocks + nSpmmStages - 1) / nSpmmStages;
    const int biTiles = (Nn + 63) / 64;
    const int perB = (biTiles + 1) / 2;
    const int biStart = 5 * NL - 1;          // first bi stage index
    const int encGy = Menc / 64;
    const int ZB = 512, CB = 1024;
    int sidx = 0, sci = 0, bci = 0;

    const float* x = enc_in;
    for (int i = 0; i < NL; ++i) {
        const size_t wOff = (size_t)i * D * D;
        int base, cnt;
        #define SPMM_CHUNK base = sci * perS; cnt = spmmBlocks - base; \
                           if (cnt < 0) cnt = 0; if (cnt > perS) cnt = perS; sci++
        #define BI_CHUNK   base = bci * perB; cnt = biTiles - base; \
                           if (cnt < 0) cnt = 0; if (cnt > perB) cnt = perB; bci++

        // --- Q/K/V projection ---
        sidx++;
        if (sidx == 1) {
            qkv2_pre<<<3 * encGy + ZB + CB, 256, 0, stream>>>(
                x, wq + wOff, wk + wOff, wv + wOff,
                bq + (size_t)i * D, bk + (size_t)i * D, bv + (size_t)i * D,
                Qb, Kb, Vb, Menc, encGy,
                side, Nn, ego, egob, 3 * encGy, ZB, CB);
        } else {
            SPMM_CHUNK;
            qkv2_spmm<<<3 * encGy + cnt, 256, 0, stream>>>(
                x, wq + wOff, wk + wOff, wv + wOff,
                bq + (size_t)i * D, bk + (size_t)i * D, bv + (size_t)i * D,
                Qb, Kb, Vb, Menc, encGy,
                egob, vals, rows, cols, side, nnz, base, 3 * encGy);
        }

        // --- attention --- (always a spmm stage: attn sidx = 5i+2 <= 5NL-3)
        sidx++;
        SPMM_CHUNK;
        attn_spmm<<<Bb * NH + cnt, 256, 0, stream>>>(
            Qb, Kb, Vb, Ob, NH,
            egob, vals, rows, cols, side, nnz, base, Bb * NH);

        // --- MHA out-proj + residual + LN1 --- (sidx = 5i+3 <= 5NL-2: spmm)
        sidx++;
        SPMM_CHUNK;
        gemm2_spmm<<<encGy + cnt, 256, 0, stream>>>(
            Ob, wo + wOff, bo + (size_t)i * D, x,
            ln1_g + (size_t)i * D, ln1_b + (size_t)i * D, XA, Menc, D, D, 0, encGy,
            egob, vals, rows, cols, side, nnz, base, encGy);

        // --- FFN up + relu ---
        sidx++;
        if (sidx >= biStart) {
            BI_CHUNK;
            gemm2_bi2<<<4 * encGy + cnt, 256, 0, stream>>>(
                XA, cw1 + (size_t)i * D * DI, cb1 + (size_t)i * DI, nullptr,
                nullptr, nullptr, Hb, Menc, DI, D, 1, encGy, 4 * encGy,
                ego, side, W1, b1, W2, b2, outAgg, Nn, base);
        } else {
            SPMM_CHUNK;
            gemm2_spmm<<<4 * encGy + cnt, 256, 0, stream>>>(
                XA, cw1 + (size_t)i * D * DI, cb1 + (size_t)i * DI, nullptr,
                nullptr, nullptr, Hb, Menc, DI, D, 1, encGy,
                egob, vals, rows, cols, side, nnz, base, 4 * encGy);
        }

        // --- FFN down + residual + LN2 ---
        sidx++;
        float* dst = (i == NL - 1) ? outX : XB;
        if (sidx >= biStart) {
            BI_CHUNK;
            gemm2_bi2<<<encGy + cnt, 256, 0, stream>>>(
                Hb, cw2 + (size_t)i * DI * D, cb2 + (size_t)i * D, XA,
                ln2_g + (size_t)i * D, ln2_b + (size_t)i * D, dst, Menc, D, DI, 0,
                encGy, encGy,
                ego, side, W1, b1, W2, b2, outAgg, Nn, base);
        } else {
            SPMM_CHUNK;
            gemm2_spmm<<<encGy + cnt, 256, 0, stream>>>(
                Hb, cw2 + (size_t)i * DI * D, cb2 + (size_t)i * D, XA,
                ln2_g + (size_t)i * D, ln2_b + (size_t)i * D, dst, Menc, D, DI, 0, encGy,
                egob, vals, rows, cols, side, nnz, base, encGy);
        }
        #undef SPMM_CHUNK
        #undef BI_CHUNK
        x = XB;
    }
}